// Round 1
// baseline (182.089 us; speedup 1.0000x reference)
//
#include <hip/hip_runtime.h>

#define WN 128
#define KN 32
#define CN 9
#define NBND 129           // W+1 boundary positions
#define NEGF (-1e30f)

// jnp floor-mod based wrap: (x + pi) % (2pi) - pi, bitwise-matching XLA's
// rem + (r<0 ? +y : 0) lowering (fmod is exact; add/sub round identically).
__device__ __forceinline__ float wrapf(float x) {
    const float PIf  = 3.14159265358979323846f;
    const float TPIf = 6.28318530717958647692f;
    float a = x + PIf;
    float r = fmodf(a, TPIf);
    if (r < 0.0f) r += TPIf;
    return r - PIf;
}

__global__ __launch_bounds__(1024) void voice_stitch(const float* __restrict__ tok,
                                                     float* __restrict__ out) {
    const int b = blockIdx.x;
    const float* T = tok + (size_t)b * WN * KN * CN;

    __shared__ float s_tot[WN][KN];            // chain totals (w>=1 used)
    __shared__ signed char s_prev[WN][KN];     // argmax predecessor or -1
    __shared__ signed char s_root[WN][KN];     // window-0 root of chain, -1 if none
    __shared__ float s_best[2][KN];            // DP carry (double-buffered)
    __shared__ unsigned s_ext[2][KN];
    __shared__ unsigned long long s_key[KN];   // per-root packed (total desc, idx asc)
    __shared__ unsigned char s_path[KN][WN];   // selected chain per root
    __shared__ float s_phi[KN][NBND];          // phase anchors per root
    __shared__ int s_we[KN];                   // w_end per root, -1 if none
    __shared__ int s_e[KN];                    // flat endpoint index per root

    const int t  = threadIdx.x;
    const int kp = t & 31;        // predecessor token index
    const int kn = t >> 5;        // successor token index (0..31)

    if (t < KN) {
        float sn0 = T[t * CN + 0];
        bool p = sn0 > 0.0f;
        s_best[0][t] = p ? sn0 : NEGF;
        s_ext[0][t]  = p ? 1u : 0u;
        s_key[t] = 0ull;
        s_we[t] = -1;
        s_root[0][t] = (signed char)t;
    }
    __syncthreads();

    // ---- Viterbi DP over windows (sequential in w, 1024-way parallel per step)
    for (int w = 1; w < WN; ++w) {
        const int rb = (w - 1) & 1, wb = w & 1;
        const float* Tp = T + ((w - 1) * KN + kp) * CN;
        const float* Tc = T + (w * KN + kn) * CN;
        float bestv = NEGF;
        if (s_ext[rb][kp]) {   // ext implies pos[prev]
            float fe = Tp[4], fs = Tc[3];
            float fm = (fe + fs) * 0.5f;
            bool ok_f = (fm <= 0.0f) || (fabsf(fe - fs) / (fm > 0.0f ? fm : 1.0f) <= 0.05f);
            float dphi = wrapf(Tc[7] - Tp[8]);
            bool ok_p = fabsf(dphi) <= 0.5f;
            float ae = Tp[6], an = Tc[5];
            float am = fmaxf(ae, an);
            bool ok_a = (am <= 0.0f) || (fabsf(ae - an) / (am > 0.0f ? am : 1.0f) <= 0.5f);
            bool posc = Tc[0] > 0.0f;
            if (ok_f && ok_p && ok_a && posc) bestv = s_best[rb][kp];
        }
        // max + first-index argmax over the 32 kp lanes (within wave halves)
        float v = bestv;
        int idx = kp;
        #pragma unroll
        for (int m = 16; m >= 1; m >>= 1) {
            float ov = __shfl_xor(v, m);
            int   oi = __shfl_xor(idx, m);
            if (ov > v || (ov == v && oi < idx)) { v = ov; idx = oi; }
        }
        if (kp == 0) {
            float sn = Tc[0];
            bool reached = v > -5e29f;          // bf > NEG*0.5
            float te = v + sn;
            bool pn = sn > 0.0f;
            s_tot[w][kn] = reached ? te : (pn ? sn : NEGF);
            signed char pv = reached ? (signed char)idx : (signed char)-1;
            s_prev[w][kn] = pv;
            s_root[w][kn] = (pv >= 0) ? s_root[w - 1][pv] : (signed char)-1;
            s_best[wb][kn] = reached ? te : NEGF;
            s_ext[wb][kn]  = reached ? 1u : 0u;
        }
        __syncthreads();
    }

    // ---- greedy == per-root argmax(total), tie -> lowest flat idx
    for (int e = KN + t; e < WN * KN; e += 1024) {
        int w = e >> 5, k = e & 31;
        if (s_prev[w][k] >= 0) {
            int r = s_root[w][k];
            unsigned ub = __float_as_uint(s_tot[w][k]);
            ub ^= (ub >> 31) ? 0xFFFFFFFFu : 0x80000000u;   // orderable map
            unsigned long long key =
                ((unsigned long long)ub << 32) | (unsigned long long)(0xFFFFFFFFu - (unsigned)e);
            atomicMax(&s_key[r], key);
        }
    }
    __syncthreads();

    // ---- backtrack selected chain + phase cumsum (one lane per root)
    if (t < KN) {
        unsigned long long key = s_key[t];
        if (key != 0ull) {
            int e = (int)(0xFFFFFFFFu - (unsigned)(key & 0xFFFFFFFFull));
            int we = e >> 5;
            s_we[t] = we;
            s_e[t] = e;
            int k = e & 31;
            for (int w = we; w > 0; --w) {
                s_path[t][w] = (unsigned char)k;
                k = s_prev[w][k];
            }
            s_path[t][0] = (unsigned char)k;

            int p0 = s_path[t][0];
            float ps0 = T[p0 * CN + 7];
            float pe_prev = T[p0 * CN + 8];
            float cum = ps0;
            s_phi[t][0] = cum;
            cum = cum + (pe_prev - ps0);        // d_first
            s_phi[t][1] = cum;
            for (int j = 1; j <= we; ++j) {
                int pj = s_path[t][j];
                float psj = T[(j * KN + pj) * CN + 7];
                float pej = T[(j * KN + pj) * CN + 8];
                float d = wrapf(psj - pe_prev) + pej - psj;   // d_gen, same assoc
                cum += d;
                s_phi[t][j + 1] = cum;
                pe_prev = pej;
            }
        }
    }
    __syncthreads();

    // ---- write anchors for selected chains (<=32 rows of 129x4 per batch)
    float* Ob = out + (size_t)b * (WN * KN) * NBND * 4;
    for (int u = t; u < KN * NBND; u += 1024) {
        int r  = u / NBND;
        int bp = u - r * NBND;
        int we = s_we[r];
        if (we < 0) continue;
        int L = we + 1;
        if (bp > L) continue;
        float aA, at, af;
        if (bp == 0) {
            const float* Tq = T + (int)s_path[r][0] * CN;
            at = Tq[1]; af = Tq[3]; aA = Tq[5];
        } else if (bp == L) {
            const float* Tq = T + (we * KN + (int)s_path[r][we]) * CN;
            at = Tq[2]; af = Tq[4]; aA = Tq[6];
        } else {
            const float* Ta = T + ((bp - 1) * KN + (int)s_path[r][bp - 1]) * CN;
            const float* Tb = T + (bp * KN + (int)s_path[r][bp]) * CN;
            at = (Ta[2] + Tb[1]) * 0.5f;
            af = (Ta[4] + Tb[3]) * 0.5f;
            aA = (Ta[6] + Tb[5]) * 0.5f;
        }
        float4 val;
        val.x = aA; val.y = at; val.z = s_phi[r][bp]; val.w = af;
        *reinterpret_cast<float4*>(Ob + ((size_t)s_e[r] * NBND + bp) * 4) = val;
    }
}

extern "C" void kernel_launch(void* const* d_in, const int* in_sizes, int n_in,
                              void* d_out, int out_size, void* d_ws, size_t ws_size,
                              hipStream_t stream) {
    const float* tok = (const float*)d_in[0];
    float* out = (float*)d_out;
    int B = in_sizes[0] / (WN * KN * CN);

    // Output is sparse (<=32 nonzero rows per batch): zero-fill, then scatter.
    hipMemsetAsync(d_out, 0, (size_t)out_size * sizeof(float), stream);
    hipLaunchKernelGGL(voice_stitch, dim3(B), dim3(1024), 0, stream, tok, out);
}